// Round 12
// baseline (788.923 us; speedup 1.0000x reference)
//
#include <hip/hip_runtime.h>
#include <hip/hip_bf16.h>

#define B_TOK 2048
#define DDIM 1024
#define FDIM 4096
#define NE 16
#define NG 2
#define BD ((long)B_TOK * DDIM)

typedef unsigned short u16;
typedef __attribute__((ext_vector_type(8))) short bf16x8;   // 8 bf16 (4 VGPRs)
typedef __attribute__((ext_vector_type(4))) float f32x4;

// ---------- helpers ----------
__device__ inline u16 f2bf(float x) {           // RNE f32 -> bf16 bits
  union { float f; unsigned u; } v; v.f = x;
  return (u16)((v.u + 0x7fffu + ((v.u >> 16) & 1u)) >> 16);
}
__device__ inline float bfround(float x) {      // f32 -> bf16 -> f32 (matches astype(bf16))
  union { float f; unsigned u; } v; v.f = x;
  v.u = ((v.u + 0x7fffu + ((v.u >> 16) & 1u)) >> 16) << 16;
  return v.f;
}
// Abramowitz-Stegun 7.1.26 erf, |eps| <= 1.5e-7
__device__ inline float fast_erf(float x) {
  float ax = fabsf(x);
  float t = __builtin_amdgcn_rcpf(1.0f + 0.3275911f * ax);
  float poly = t * (0.254829592f + t * (-0.284496736f + t * (1.421413741f +
               t * (-1.453152027f + t * 1.061405429f))));
  float r = 1.0f - poly * __expf(-ax * ax);
  return copysignf(r, x);
}
__device__ inline float gelu_exact(float x) {
  return 0.5f * x * (1.0f + fast_erf(x * 0.70710678118654752440f));
}
__device__ inline void gload16(const void* g, void* l) {
  // LDS dest is wave-uniform base; HW adds lane*16 (guide m104/m108).
  __builtin_amdgcn_global_load_lds((const __attribute__((address_space(1))) void*)g,
                                   (__attribute__((address_space(3))) void*)l, 16, 0, 0);
}
__device__ inline float waveSum(float v) {
  v += __shfl_down(v, 32); v += __shfl_down(v, 16); v += __shfl_down(v, 8);
  v += __shfl_down(v, 4);  v += __shfl_down(v, 2);  v += __shfl_down(v, 1);
  return v;
}

// ---------- gating + loss partials ----------
__global__ __launch_bounds__(256) void gating_kernel(
    const float* __restrict__ logits, const int* __restrict__ masks,
    float* __restrict__ gates, float* __restrict__ loss)
{
  const int b = blockIdx.x * 256 + threadIdx.x;       // grid 8 x 256 == 2048
  const int lane = threadIdx.x & 63;
  const float* lr = logits + (long)b * NE;
  const int*   mr = masks  + (long)b * NE;
  float raw[NE]; int mk[NE];
  float mx = -1e30f;
#pragma unroll
  for (int e = 0; e < NE; ++e) { raw[e] = lr[e]; mx = fmaxf(mx, raw[e]); }
  float s = 0.f;
#pragma unroll
  for (int e = 0; e < NE; ++e) { raw[e] = expf(raw[e] - mx); s += raw[e]; }
  float inv = 1.0f / s;
#pragma unroll
  for (int e = 0; e < NE; ++e) raw[e] *= inv;
  float gs = 0.f;
#pragma unroll
  for (int e = 0; e < NE; ++e) { mk[e] = (mr[e] == 1); gs += mk[e] ? raw[e] : 0.f; }
  float ginv = 1.0f / (gs + 1e-9f);
  float* gr = gates + (long)b * NE;
#pragma unroll
  for (int e = 0; e < NE; ++e) gr[e] = (mk[e] ? raw[e] : 0.f) * ginv;
#pragma unroll
  for (int e = 0; e < NE; ++e) {
    float cs = waveSum(raw[e]);
    float cc = waveSum(mk[e] ? 1.f : 0.f);
    if (lane == 0) { atomicAdd(&loss[e], cs); atomicAdd(&loss[NE + e], cc); }
  }
  float t = waveSum(gs);
  if (lane == 0) atomicAdd(&loss[32], t);
}

__global__ void finalize_loss(const float* __restrict__ loss, float* __restrict__ out2) {
  if (threadIdx.x == 0) {
    float aug = 0.f;
    for (int e = 0; e < NE; ++e)
      aug += (loss[e] / (float)B_TOK) * (loss[NE + e] / (float)B_TOK);
    aug *= (1.0f / NE);
    float s = loss[32] / (float)B_TOK;
    out2[0] = aug;
    out2[1] = (1.f - s) * (1.f - s);
  }
}

// ---------- deterministic per-expert token compaction + inverse map ----------
__global__ __launch_bounds__(256) void compact_kernel(
    const int* __restrict__ masks, int* __restrict__ tok,
    int* __restrict__ pos, int* __restrict__ cnts)
{
  const int e = blockIdx.x, tid = threadIdx.x;
  const int lane = tid & 63, wave = tid >> 6;
  __shared__ int wcnt[4];
  __shared__ int runbase;
  if (tid == 0) runbase = 0;
  __syncthreads();
  for (int b0 = 0; b0 < B_TOK; b0 += 256) {
    int b = b0 + tid;
    int m = (masks[(long)b * NE + e] == 1);
    unsigned long long bal = __ballot(m);
    int pre = __popcll(bal & ((1ull << lane) - 1ull));
    if (lane == 0) wcnt[wave] = __popcll(bal);
    __syncthreads();
    int base = runbase;
    for (int w = 0; w < wave; ++w) base += wcnt[w];
    if (m) {
      int p = base + pre;
      tok[(e << 11) + p] = b;
      pos[(long)b * NE + e] = p;
    } else {
      pos[(long)b * NE + e] = -1;
    }
    __syncthreads();
    if (tid == 0) runbase += wcnt[0] + wcnt[1] + wcnt[2] + wcnt[3];
    __syncthreads();
  }
  const int cnt = runbase;
  const int cnt_pad = (cnt + 255) & ~255;              // 256-row tiles
  for (int i = cnt + tid; i < cnt_pad; i += 256)
    tok[(e << 11) + i] = 0;          // safe row; pad output rows never read
  if (tid == 0) { cnts[e] = cnt; cnts[NE + e] = cnt_pad; }
}

// ---------- x f32 -> bf16 ----------
__global__ __launch_bounds__(256) void cvt_x_kernel(const float* __restrict__ x, u16* __restrict__ xb) {
  long i = ((long)blockIdx.x * 256 + threadIdx.x) * 4;
  float4 v = *(const float4*)&x[i];
  ushort4 o; o.x = f2bf(v.x); o.y = f2bf(v.y); o.z = f2bf(v.z); o.w = f2bf(v.w);
  *(ushort4*)&xb[i] = o;
}

// ---------- moe bias: moe_bias[b,d] = sum_e gates[b,e]*eb[e,d] ----------
__global__ __launch_bounds__(256) void bias_init_kernel(
    const float* __restrict__ gates, const float* __restrict__ eb,
    float* __restrict__ moe_bias)
{
  long i = (long)blockIdx.x * 256 + threadIdx.x;       // grid 8192 -> B*D
  int b = (int)(i >> 10), d = (int)(i & 1023);
  const float* gr = gates + (long)b * NE;
  float s = 0.f;
#pragma unroll
  for (int e = 0; e < NE; ++e) s += gr[e] * eb[e * DDIM + d];
  moe_bias[i] = s;
}

// ---------- transpose + f32->bf16: src [R,C] -> dst [C,R] ----------
__global__ __launch_bounds__(256) void transpose_cvt(
    const float* __restrict__ src, u16* __restrict__ dst,
    int R, int C, long sZ, long dZ)
{
  __shared__ float t[64][65];
  const float* s = src + (long)blockIdx.z * sZ;
  u16* d = dst + (long)blockIdx.z * dZ;
  const int c0 = blockIdx.x * 64, r0 = blockIdx.y * 64;
  const int tid = threadIdx.x;
#pragma unroll
  for (int it = 0; it < 4; ++it) {
    int idx = tid + it * 256;
    int r = idx >> 4, cq = (idx & 15) * 4;
    float4 v = *(const float4*)&s[(long)(r0 + r) * C + c0 + cq];
    t[r][cq] = v.x; t[r][cq + 1] = v.y; t[r][cq + 2] = v.z; t[r][cq + 3] = v.w;
  }
  __syncthreads();
#pragma unroll
  for (int it = 0; it < 4; ++it) {
    int idx = tid + it * 256;
    int c = idx >> 4, rq = (idx & 15) * 4;
    ushort4 o;
    o.x = f2bf(t[rq][c]); o.y = f2bf(t[rq+1][c]); o.z = f2bf(t[rq+2][c]); o.w = f2bf(t[rq+3][c]);
    *(ushort4*)&d[(long)(c0 + c) * R + r0 + rq] = o;
  }
}

// ---------- 256x128 bf16 MFMA GEMM — 8-wave, BK=64, 4 quadrant-phases/K-tile,
// 3-buffer ring (stage distance 2), counted vmcnt(6) (never 0 until tail),
// setprio around MFMA clusters, conflict-free XOR-swizzled LDS (r6/r7-verified
// mapping: SQ_LDS_BANK_CONFLICT == 0 on HW). klen is RUNTIME (r9 lesson: do not
// make constexpr — full unroll blows VGPR/occupancy).
// Safety proofs (per round-12 derivation):
//  - stage target buf (t+2)%3 was last read at tile t-1, sealed by barrier.
//  - vmcnt(6) at tile t end: issued 12+6(t+1), outstanding<=6 => tiles <=t+1
//    fully landed before tile t+1's reads. Tail: vmcnt(0) once.
// MODE 0: in-proj (gather via tok when non-null). H[z] = bf16(gelu(acc)).
// MODE 1: out-proj routed. C[z] = acc (f32, pure write).
// MODE 2: out-proj general, K-split 2: z = g*2+ks. C[z] = acc (disjoint slices).
template<int MODE>
__global__ __launch_bounds__(512, 2) void gemm8p(
    const u16* __restrict__ A, int lda, long aZ,
    const u16* __restrict__ Bm, int ldb,
    int klen,
    u16* __restrict__ H, long hZ,
    float* __restrict__ C, long cZ,
    const int* __restrict__ tok, const int* __restrict__ cnts, int ebase)
{
  // bijective chunked XCD swizzle (T div 8) + 4x4 super-tile raster within z
  int lin = ((int)blockIdx.z * gridDim.y + blockIdx.y) * gridDim.x + blockIdx.x;
  const int T = gridDim.x * gridDim.y * gridDim.z;
  lin = (lin & 7) * (T >> 3) + (lin >> 3);
  const int PZ = gridDim.x * gridDim.y;
  const int z = lin / PZ;
  const int r = lin - z * PZ;
  const int nSx = gridDim.x >> 2;
  const int st4 = r >> 4, pos = r & 15;
  const int bx = ((st4 % nSx) << 2) + (pos & 3);
  const int by = ((st4 / nSx) << 2) + (pos >> 2);

  const int m0 = by * 256, n0 = bx * 128;
  if (MODE != 2 && cnts && m0 >= cnts[NE + ebase + z]) return;

  __shared__ u16 lds[3][24576];        // per buf: A 256x64 @0..16383, B 128x64 @16384..

  const int zb = (MODE == 2) ? (z >> 1) : z;
  const int ks = (MODE == 2) ? (z & 1) * klen : 0;
  const u16* Az = A + (long)((MODE == 0) ? 0 : zb) * aZ;
  const u16* Bz = Bm + (long)zb * ((long)DDIM * FDIM);

  const int tid = threadIdx.x, lane = tid & 63, wave = tid >> 6;
  const int wr = wave >> 1, wc = wave & 1;     // 4M x 2N waves of 64x64
  const int fr = lane & 15;

  // staging: chunk = 64 rows x 64 elems (8KB, 1 gload/thread).
  // thread covers row wave*8+(lane>>3), k granule (lane&7)*8; source k
  // pre-swizzled by ((row&7)<<3) so linear LDS + swizzled reads match (rule #21).
  const int srow = wave * 8 + (lane >> 3);
  const int skey = ((lane & 7) << 3) ^ ((lane >> 3) << 3);
  const u16* gA[4];
  const u16* gB[2];
#pragma unroll
  for (int c = 0; c < 4; ++c) {
    int rr = m0 + c * 64 + srow;
    if (MODE == 0 && tok) rr = tok[((ebase + z) << 11) + rr];
    gA[c] = Az + (long)rr * lda + ks + skey;
  }
#pragma unroll
  for (int c = 0; c < 2; ++c)
    gB[c] = Bz + (long)(n0 + c * 64 + srow) * ldb + ks + skey;

  auto stA = [&](int buf, int t, int c) {
    gload16(gA[c] + (t << 6), &lds[buf][c * 4096 + wave * 512]);
  };
  auto stB = [&](int buf, int t, int c) {
    gload16(gB[c] + (t << 6), &lds[buf][16384 + c * 4096 + wave * 512]);
  };
  // fragment reads: row&7 == fr&7, so read k XORs with ((fr&7)<<3)
  auto rdA = [&](int buf, int mi, int kh) -> bf16x8 {
    int row = wr * 64 + mi * 16 + fr;
    int keff = ((lane >> 4) * 8 + kh * 32) ^ ((fr & 7) << 3);
    return *(const bf16x8*)(&lds[buf][row * 64 + keff]);
  };
  auto rdB = [&](int buf, int ni, int kh) -> bf16x8 {
    int row = wc * 64 + ni * 16 + fr;
    int keff = ((lane >> 4) * 8 + kh * 32) ^ ((fr & 7) << 3);
    return *(const bf16x8*)(&lds[buf][16384 + row * 64 + keff]);
  };

  f32x4 acc[4][4];
  f32x4 zero = {0.f, 0.f, 0.f, 0.f};
#pragma unroll
  for (int mi = 0; mi < 4; ++mi)
#pragma unroll
    for (int ni = 0; ni < 4; ++ni) acc[mi][ni] = zero;

  const int nt = klen >> 6;            // K-tiles of 64 (nt >= 3 for all launches)
  // prologue: stage tiles 0,1 (12 loads), wait tile 0 (6 in flight)
#pragma unroll
  for (int c = 0; c < 4; ++c) stA(0, 0, c);
  stB(0, 0, 0); stB(0, 0, 1);
#pragma unroll
  for (int c = 0; c < 4; ++c) stA(1, 1, c);
  stB(1, 1, 0); stB(1, 1, 1);
  asm volatile("s_waitcnt vmcnt(6)" ::: "memory");
  __builtin_amdgcn_s_barrier();
  asm volatile("" ::: "memory");

#define PH_MFMA(QM, QN)                                                        \
  __builtin_amdgcn_s_barrier();                                                \
  __builtin_amdgcn_sched_barrier(0);                                           \
  __builtin_amdgcn_s_setprio(1);                                               \
  _Pragma("unroll")                                                            \
  for (int kh = 0; kh < 2; ++kh)                                               \
    _Pragma("unroll")                                                          \
    for (int m2 = 0; m2 < 2; ++m2)                                             \
      _Pragma("unroll")                                                        \
      for (int n2 = 0; n2 < 2; ++n2)                                           \
        acc[QM * 2 + m2][QN * 2 + n2] = __builtin_amdgcn_mfma_f32_16x16x32_bf16( \
            af[m2][kh], bf[QN * 2 + n2][kh], acc[QM * 2 + m2][QN * 2 + n2], 0, 0, 0); \
  __builtin_amdgcn_s_setprio(0);                                               \
  __builtin_amdgcn_sched_barrier(0);                                           \
  asm volatile("" ::: "memory");                                               \
  __builtin_amdgcn_s_barrier();

  int buf = 0;
  for (int t = 0; t < nt; ++t) {
    int sb = buf + 2; if (sb >= 3) sb -= 3;            // (t+2)%3
    const bool stg = (t + 2 < nt);
    bf16x8 af[2][2], bf[4][2];
    // phase 0: A frags mi0-1, B frags ni0-1; stage A chunks 0,1
    af[0][0] = rdA(buf, 0, 0); af[0][1] = rdA(buf, 0, 1);
    af[1][0] = rdA(buf, 1, 0); af[1][1] = rdA(buf, 1, 1);
    bf[0][0] = rdB(buf, 0, 0); bf[0][1] = rdB(buf, 0, 1);
    bf[1][0] = rdB(buf, 1, 0); bf[1][1] = rdB(buf, 1, 1);
    if (stg) { stA(sb, t + 2, 0); stA(sb, t + 2, 1); }
    asm volatile("" ::: "memory");
    PH_MFMA(0, 0)
    // phase 1: B frags ni2-3; stage A chunks 2,3
    bf[2][0] = rdB(buf, 2, 0); bf[2][1] = rdB(buf, 2, 1);
    bf[3][0] = rdB(buf, 3, 0); bf[3][1] = rdB(buf, 3, 1);
    if (stg) { stA(sb, t + 2, 2); stA(sb, t + 2, 3); }
    asm volatile("" ::: "memory");
    PH_MFMA(0, 1)
    // phase 2: A frags mi2-3 (overwrite af); stage B chunk 0
    af[0][0] = rdA(buf, 2, 0); af[0][1] = rdA(buf, 2, 1);
    af[1][0] = rdA(buf, 3, 0); af[1][1] = rdA(buf, 3, 1);
    if (stg) stB(sb, t + 2, 0);
    asm volatile("" ::: "memory");
    PH_MFMA(1, 0)
    // phase 3: stage B chunk 1; tile-boundary counted vmcnt
    if (stg) {
      stB(sb, t + 2, 1);
      asm volatile("s_waitcnt vmcnt(6)" ::: "memory");
    } else if (t + 1 < nt) {
      asm volatile("s_waitcnt vmcnt(0)" ::: "memory");
    }
    asm volatile("" ::: "memory");
    PH_MFMA(1, 1)
    buf = buf + 1; if (buf >= 3) buf = 0;
  }
#undef PH_MFMA

  // epilogue: C/D map col=lane&15, row=(lane>>4)*4+j  (guide m89/m91; r5-verified)
  const int er = m0 + wr * 64 + (lane >> 4) * 4;
  const int ec = n0 + wc * 64 + fr;
  if (MODE == 0) {
    u16* Hz = H + (long)z * hZ;
#pragma unroll
    for (int mi = 0; mi < 4; ++mi)
#pragma unroll
      for (int ni = 0; ni < 4; ++ni) {
        f32x4 v = acc[mi][ni];
        int rb = er + mi * 16, cb = ec + ni * 16;
#pragma unroll
        for (int j = 0; j < 4; ++j)
          Hz[(long)(rb + j) * FDIM + cb] = f2bf(gelu_exact(v[j]));
      }
  } else {
    float* Cz = (MODE == 1) ? (C + (long)(ebase + z) * cZ) : (C + (long)z * cZ);
#pragma unroll
    for (int mi = 0; mi < 4; ++mi)
#pragma unroll
      for (int ni = 0; ni < 4; ++ni) {
        f32x4 v = acc[mi][ni];
        int rb = er + mi * 16, cb = ec + ni * 16;
#pragma unroll
        for (int j = 0; j < 4; ++j)
          Cz[(long)(rb + j) * DDIM + cb] = v[j];
      }
  }
}

// ---------- combine (gate-weighted gather) + general + residual + LayerNorm ----------
__global__ __launch_bounds__(256) void combine_ln_kernel(
    const float* __restrict__ x, const float* __restrict__ moe_bias,
    const float* __restrict__ Eout, const float* __restrict__ gen_p,
    const float* __restrict__ gb,
    const int* __restrict__ pos, const float* __restrict__ gates,
    const float* __restrict__ gamma, const float* __restrict__ beta,
    float* __restrict__ out)
{
  const int b = blockIdx.x, tid = threadIdx.x;
  const int lane = tid & 63, wave = tid >> 6;
  const long base = (long)b * DDIM;
  __shared__ int posr[NE];
  __shared__ float gr[NE];
  __shared__ float red[4];
  if (tid < NE) { posr[tid] = pos[(long)b * NE + tid]; gr[tid] = gates[(long)b * NE + tid]; }
  __syncthreads();
  float y[4];
  float ls = 0.f;
#pragma unroll
  for (int i = 0; i < 4; ++i) {
    int d = tid + i * 256;
    long idx = base + d;
    float moe = moe_bias[idx];
#pragma unroll
    for (int e = 0; e < NE; ++e) {
      int p = posr[e];                                  // block-uniform -> no divergence
      if (p >= 0) moe += gr[e] * Eout[((long)e * B_TOK + p) * DDIM + d];
    }
    moe = bfround(moe);                                 // matches ref's bf16 cast of moe_out
    float ge = gb[d] + gb[DDIM + d];
#pragma unroll
    for (int sl = 0; sl < 4; ++sl) ge += gen_p[(long)sl * BD + idx];
    y[i] = moe + ge + x[idx];
    ls += y[i];
  }
  float t = waveSum(ls);
  if (lane == 0) red[wave] = t;
  __syncthreads();
  float mean = (red[0] + red[1] + red[2] + red[3]) * (1.0f / DDIM);
  __syncthreads();
  float vs = 0.f;
#pragma unroll
  for (int i = 0; i < 4; ++i) { float d2 = y[i] - mean; vs += d2 * d2; }
  t = waveSum(vs);
  if (lane == 0) red[wave] = t;
  __syncthreads();
  float var = (red[0] + red[1] + red[2] + red[3]) * (1.0f / DDIM);
  float inv = rsqrtf(var + 1e-5f);
#pragma unroll
  for (int i = 0; i < 4; ++i) {
    int d = tid + i * 256;
    out[base + d] = (y[i] - mean) * inv * gamma[d] + beta[d];
  }
}

// ---------- orchestration ----------
extern "C" void kernel_launch(void* const* d_in, const int* in_sizes, int n_in,
                              void* d_out, int out_size, void* d_ws, size_t ws_size,
                              hipStream_t stream)
{
  const float* x      = (const float*)d_in[0];
  const float* logits = (const float*)d_in[1];
  const int*   masks  = (const int*)d_in[2];
  const float* ew_in  = (const float*)d_in[3];
  const float* ew_out = (const float*)d_in[4];
  const float* eb_out = (const float*)d_in[5];
  const float* gw_in  = (const float*)d_in[6];
  const float* gw_out = (const float*)d_in[7];
  const float* gb_out = (const float*)d_in[8];
  const float* gamma  = (const float*)d_in[9];
  const float* beta   = (const float*)d_in[10];
  float* out = (float*)d_out;

  char* w = (char*)d_ws;
  size_t off = 0;
  auto alloc = [&](size_t bytes) -> void* {
    off = (off + 4095) & ~(size_t)4095;
    void* p = w + off; off += bytes; return p;
  };
  const long DF = (long)DDIM * FDIM;          // 4.19M elems
  const long BF = (long)B_TOK * FDIM;         // 8.39M elems

  float* gates    = (float*)alloc((size_t)B_TOK * NE * 4);
  float* loss     = (float*)alloc(64 * 4);
  int*   tok      = (int*)alloc((size_t)NE * B_TOK * 4);
  int*   pos      = (int*)alloc((size_t)B_TOK * NE * 4);
  int*   cnts     = (int*)alloc(2 * NE * 4);
  u16*   xb       = (u16*)alloc((size_t)BD * 2);
  float* moe_bias = (float*)alloc((size_t)BD * 4);
  float* gen_p    = (float*)alloc(4 * (size_t)BD * 4);           // 4 slices (2g x 2ks)
  float* Eout     = (float*)alloc((size_t)NE * BD * 4);          // per-expert compact f32

  // routed chunk size adaptive to remaining ws
  const size_t per = 2 * (size_t)DF * 2 + (size_t)BF * 2 + 3 * 4096; // WinT+WoutT+Hb per expert
  int CE = 16;
  while (CE > 1 && off + (size_t)CE * per > ws_size) CE >>= 1;
  u16* WinT  = (u16*)alloc((size_t)CE * DF * 2);
  u16* WoutT = (u16*)alloc((size_t)CE * DF * 2);
  u16* Hb    = (u16*)alloc((size_t)CE * BF * 2);

  hipMemsetAsync(loss, 0, 64 * 4, stream);
  gating_kernel<<<8, 256, 0, stream>>>(logits, masks, gates, loss);
  finalize_loss<<<1, 64, 0, stream>>>(loss, out + BD);
  compact_kernel<<<NE, 256, 0, stream>>>(masks, tok, pos, cnts);
  cvt_x_kernel<<<2048, 256, 0, stream>>>(x, xb);
  bias_init_kernel<<<8192, 256, 0, stream>>>(gates, eb_out, moe_bias);

  for (int e0 = 0; e0 < NE; e0 += CE) {
    transpose_cvt<<<dim3(FDIM/64, DDIM/64, CE), 256, 0, stream>>>(
        ew_in + (long)e0 * DF, WinT, DDIM, FDIM, DF, DF);
    transpose_cvt<<<dim3(DDIM/64, FDIM/64, CE), 256, 0, stream>>>(
        ew_out + (long)e0 * DF, WoutT, FDIM, DDIM, DF, DF);
    // in-proj: [cnt_pad,1024] x [4096,1024]^T -> Hb (bf16 gelu), K=1024
    gemm8p<0><<<dim3(FDIM/128, B_TOK/256, CE), 512, 0, stream>>>(
        xb, DDIM, 0L, WinT, DDIM, DDIM,
        Hb, BF, nullptr, 0L, tok, cnts, e0);
    // out-proj: [cnt_pad,4096] x [1024,4096]^T -> Eout (f32, compact, full-K)
    gemm8p<1><<<dim3(DDIM/128, B_TOK/256, CE), 512, 0, stream>>>(
        Hb, FDIM, BF, WoutT, FDIM, FDIM,
        nullptr, 0L, Eout, BD, nullptr, cnts, e0);
  }

  // general experts: reuse WinT/WoutT/Hb scratch (runs after routed consumed Hb)
  transpose_cvt<<<dim3(FDIM/64, DDIM/64, NG), 256, 0, stream>>>(
      gw_in, WinT, DDIM, FDIM, DF, DF);
  transpose_cvt<<<dim3(DDIM/64, FDIM/64, NG), 256, 0, stream>>>(
      gw_out, WoutT, FDIM, DDIM, DF, DF);
  gemm8p<0><<<dim3(FDIM/128, B_TOK/256, NG), 512, 0, stream>>>(
      xb, DDIM, 0L, WinT, DDIM, DDIM,
      Hb, BF, nullptr, 0L, nullptr, nullptr, 0);
  // general out-proj: K-split 2 (z = g*2+ks, klen=2048), disjoint slice writes
  gemm8p<2><<<dim3(DDIM/128, B_TOK/256, NG * 2), 512, 0, stream>>>(
      Hb, FDIM, BF, WoutT, FDIM, FDIM / 2,
      nullptr, 0L, gen_p, BD, nullptr, nullptr, 0);

  combine_ln_kernel<<<B_TOK, 256, 0, stream>>>(
      x, moe_bias, Eout, gen_p, gb_out, pos, gates, gamma, beta, out);
}

// Round 13
// 764.176 us; speedup vs baseline: 1.0324x; 1.0324x over previous
//
#include <hip/hip_runtime.h>
#include <hip/hip_bf16.h>

#define B_TOK 2048
#define DDIM 1024
#define FDIM 4096
#define NE 16
#define NG 2
#define BD ((long)B_TOK * DDIM)

typedef unsigned short u16;
typedef __attribute__((ext_vector_type(8))) short bf16x8;   // 8 bf16 (4 VGPRs)
typedef __attribute__((ext_vector_type(4))) float f32x4;

// ---------- helpers ----------
__device__ inline u16 f2bf(float x) {           // RNE f32 -> bf16 bits
  union { float f; unsigned u; } v; v.f = x;
  return (u16)((v.u + 0x7fffu + ((v.u >> 16) & 1u)) >> 16);
}
__device__ inline float bfround(float x) {      // f32 -> bf16 -> f32 (matches astype(bf16))
  union { float f; unsigned u; } v; v.f = x;
  v.u = ((v.u + 0x7fffu + ((v.u >> 16) & 1u)) >> 16) << 16;
  return v.f;
}
// Abramowitz-Stegun 7.1.26 erf, |eps| <= 1.5e-7
__device__ inline float fast_erf(float x) {
  float ax = fabsf(x);
  float t = __builtin_amdgcn_rcpf(1.0f + 0.3275911f * ax);
  float poly = t * (0.254829592f + t * (-0.284496736f + t * (1.421413741f +
               t * (-1.453152027f + t * 1.061405429f))));
  float r = 1.0f - poly * __expf(-ax * ax);
  return copysignf(r, x);
}
__device__ inline float gelu_exact(float x) {
  return 0.5f * x * (1.0f + fast_erf(x * 0.70710678118654752440f));
}
__device__ inline void gload16(const void* g, void* l) {
  // LDS dest is wave-uniform base; HW adds lane*16 (guide m104/m108).
  __builtin_amdgcn_global_load_lds((const __attribute__((address_space(1))) void*)g,
                                   (__attribute__((address_space(3))) void*)l, 16, 0, 0);
}
__device__ inline float waveSum(float v) {
  v += __shfl_down(v, 32); v += __shfl_down(v, 16); v += __shfl_down(v, 8);
  v += __shfl_down(v, 4);  v += __shfl_down(v, 2);  v += __shfl_down(v, 1);
  return v;
}

// ---------- gating + loss partials ----------
__global__ __launch_bounds__(256) void gating_kernel(
    const float* __restrict__ logits, const int* __restrict__ masks,
    float* __restrict__ gates, float* __restrict__ loss)
{
  const int b = blockIdx.x * 256 + threadIdx.x;       // grid 8 x 256 == 2048
  const int lane = threadIdx.x & 63;
  const float* lr = logits + (long)b * NE;
  const int*   mr = masks  + (long)b * NE;
  float raw[NE]; int mk[NE];
  float mx = -1e30f;
#pragma unroll
  for (int e = 0; e < NE; ++e) { raw[e] = lr[e]; mx = fmaxf(mx, raw[e]); }
  float s = 0.f;
#pragma unroll
  for (int e = 0; e < NE; ++e) { raw[e] = expf(raw[e] - mx); s += raw[e]; }
  float inv = 1.0f / s;
#pragma unroll
  for (int e = 0; e < NE; ++e) raw[e] *= inv;
  float gs = 0.f;
#pragma unroll
  for (int e = 0; e < NE; ++e) { mk[e] = (mr[e] == 1); gs += mk[e] ? raw[e] : 0.f; }
  float ginv = 1.0f / (gs + 1e-9f);
  float* gr = gates + (long)b * NE;
#pragma unroll
  for (int e = 0; e < NE; ++e) gr[e] = (mk[e] ? raw[e] : 0.f) * ginv;
#pragma unroll
  for (int e = 0; e < NE; ++e) {
    float cs = waveSum(raw[e]);
    float cc = waveSum(mk[e] ? 1.f : 0.f);
    if (lane == 0) { atomicAdd(&loss[e], cs); atomicAdd(&loss[NE + e], cc); }
  }
  float t = waveSum(gs);
  if (lane == 0) atomicAdd(&loss[32], t);
}

__global__ void finalize_loss(const float* __restrict__ loss, float* __restrict__ out2) {
  if (threadIdx.x == 0) {
    float aug = 0.f;
    for (int e = 0; e < NE; ++e)
      aug += (loss[e] / (float)B_TOK) * (loss[NE + e] / (float)B_TOK);
    aug *= (1.0f / NE);
    float s = loss[32] / (float)B_TOK;
    out2[0] = aug;
    out2[1] = (1.f - s) * (1.f - s);
  }
}

// ---------- deterministic per-expert token compaction + inverse map ----------
__global__ __launch_bounds__(256) void compact_kernel(
    const int* __restrict__ masks, int* __restrict__ tok,
    int* __restrict__ pos, int* __restrict__ cnts)
{
  const int e = blockIdx.x, tid = threadIdx.x;
  const int lane = tid & 63, wave = tid >> 6;
  __shared__ int wcnt[4];
  __shared__ int runbase;
  if (tid == 0) runbase = 0;
  __syncthreads();
  for (int b0 = 0; b0 < B_TOK; b0 += 256) {
    int b = b0 + tid;
    int m = (masks[(long)b * NE + e] == 1);
    unsigned long long bal = __ballot(m);
    int pre = __popcll(bal & ((1ull << lane) - 1ull));
    if (lane == 0) wcnt[wave] = __popcll(bal);
    __syncthreads();
    int base = runbase;
    for (int w = 0; w < wave; ++w) base += wcnt[w];
    if (m) {
      int p = base + pre;
      tok[(e << 11) + p] = b;
      pos[(long)b * NE + e] = p;
    } else {
      pos[(long)b * NE + e] = -1;
    }
    __syncthreads();
    if (tid == 0) runbase += wcnt[0] + wcnt[1] + wcnt[2] + wcnt[3];
    __syncthreads();
  }
  const int cnt = runbase;
  const int cnt_pad = (cnt + 127) & ~127;
  for (int i = cnt + tid; i < cnt_pad; i += 256)
    tok[(e << 11) + i] = 0;          // safe row; pad output rows never read
  if (tid == 0) { cnts[e] = cnt; cnts[NE + e] = cnt_pad; }
}

// ---------- x f32 -> bf16 ----------
__global__ __launch_bounds__(256) void cvt_x_kernel(const float* __restrict__ x, u16* __restrict__ xb) {
  long i = ((long)blockIdx.x * 256 + threadIdx.x) * 4;
  float4 v = *(const float4*)&x[i];
  ushort4 o; o.x = f2bf(v.x); o.y = f2bf(v.y); o.z = f2bf(v.z); o.w = f2bf(v.w);
  *(ushort4*)&xb[i] = o;
}

// ---------- moe bias: moe_bias[b,d] = sum_e gates[b,e]*eb[e,d] ----------
__global__ __launch_bounds__(256) void bias_init_kernel(
    const float* __restrict__ gates, const float* __restrict__ eb,
    float* __restrict__ moe_bias)
{
  long i = (long)blockIdx.x * 256 + threadIdx.x;       // grid 8192 -> B*D
  int b = (int)(i >> 10), d = (int)(i & 1023);
  const float* gr = gates + (long)b * NE;
  float s = 0.f;
#pragma unroll
  for (int e = 0; e < NE; ++e) s += gr[e] * eb[e * DDIM + d];
  moe_bias[i] = s;
}

// ---------- transpose + f32->bf16: src [R,C] -> dst [C,R] ----------
__global__ __launch_bounds__(256) void transpose_cvt(
    const float* __restrict__ src, u16* __restrict__ dst,
    int R, int C, long sZ, long dZ)
{
  __shared__ float t[64][65];
  const float* s = src + (long)blockIdx.z * sZ;
  u16* d = dst + (long)blockIdx.z * dZ;
  const int c0 = blockIdx.x * 64, r0 = blockIdx.y * 64;
  const int tid = threadIdx.x;
#pragma unroll
  for (int it = 0; it < 4; ++it) {
    int idx = tid + it * 256;
    int r = idx >> 4, cq = (idx & 15) * 4;
    float4 v = *(const float4*)&s[(long)(r0 + r) * C + c0 + cq];
    t[r][cq] = v.x; t[r][cq + 1] = v.y; t[r][cq + 2] = v.z; t[r][cq + 3] = v.w;
  }
  __syncthreads();
#pragma unroll
  for (int it = 0; it < 4; ++it) {
    int idx = tid + it * 256;
    int c = idx >> 4, rq = (idx & 15) * 4;
    ushort4 o;
    o.x = f2bf(t[rq][c]); o.y = f2bf(t[rq+1][c]); o.z = f2bf(t[rq+2][c]); o.w = f2bf(t[rq+3][c]);
    *(ushort4*)&d[(long)(c0 + c) * R + r0 + rq] = o;
  }
}

// ---------- 128x128 bf16 MFMA GEMM — r5-validated 3-buffer counted-vmcnt ring,
// + 4x4 super-tile raster within each z (bijective; chunk alignment preserved:
// 16 z per dispatch => each XCD chunk covers exactly 2 experts).
// klen is a RUNTIME arg on purpose (constexpr K unrolled the t-loop in r9:
// VGPR 84->100, occupancy halved). Do not make it constexpr.
// MODE 0 (in-proj): A rows gathered via tok (tok!=null) else identity.
//   Epilogue: H[zi] = bf16(gelu(acc)).
// MODE 1 (out-proj routed): A = H[zi] compact rows, full-K. C[ebase+zi] = acc.
// MODE 2 (out-proj general): bz = g*4+ks, K-split 4, klen=FDIM/4.
//   C[bz] = acc (disjoint per-slice tiles -> pure write).
template<int MODE>
__global__ __launch_bounds__(256) void gemm128(
    const u16* __restrict__ A, int lda, long aZ,
    const u16* __restrict__ Bm, int ldb, long bZ,
    int klen,
    u16* __restrict__ H, long hZ,
    float* __restrict__ C, long cZ,
    const int* __restrict__ tok, const int* __restrict__ cnts, int ebase)
{
  // bijective chunked XCD swizzle (T divisible by 8 by construction)
  int lin = ((int)blockIdx.z * gridDim.y + blockIdx.y) * gridDim.x + blockIdx.x;
  const int T = gridDim.x * gridDim.y * gridDim.z;
  lin = (lin & 7) * (T >> 3) + (lin >> 3);
  // 4x4 super-tile decode within z: consecutive lin traverse a 4x4 tile block
  // (gridDim.x, gridDim.y both divisible by 4 for all launches here).
  const int PZ = gridDim.x * gridDim.y;
  const int bz = lin / PZ;
  const int r  = lin - bz * PZ;
  const int nSx = gridDim.x >> 2;
  const int st = r >> 4, pos = r & 15;
  const int bx = ((st % nSx) << 2) + (pos & 3);
  const int by = ((st / nSx) << 2) + (pos >> 2);

  const int zi = (MODE == 2) ? (bz >> 2) : bz;
  const int ks = (MODE == 2) ? (bz & 3) * klen : 0;
  const int m0 = by * 128, n0 = bx * 128;
  if (MODE != 2 && cnts && m0 >= cnts[NE + ebase + zi]) return;

  __shared__ u16 sA[3][128 * 32];
  __shared__ u16 sB[3][128 * 32];
  const u16* Az = A + (long)zi * aZ;
  const u16* Bz = Bm + (long)zi * bZ;
  const int tid = threadIdx.x, lane = tid & 63, wave = tid >> 6;

  // staging: linear LDS, 2 passes of 16B/thread per operand
  const int off = tid * 16;            // byte offset in 8KB tile (pass 0)
  const int sr  = off >> 6;            // row 0..63 (64B per row of 32 bf16)
  const int ske = (off & 63) >> 1;     // k element offset within row
  int arow0 = m0 + sr, arow1 = m0 + sr + 64;
  if (MODE == 0 && tok) {              // gather source rows (per-lane global ok)
    const int* tz = tok + ((ebase + zi) << 11);
    arow0 = tz[arow0]; arow1 = tz[arow1];
  }
  const u16* gA0 = Az + (long)arow0 * lda + ks + ske;
  const u16* gA1 = Az + (long)arow1 * lda + ks + ske;
  const u16* gB0 = Bz + (long)(n0 + sr) * ldb + ks + ske;
  const u16* gB1 = Bz + (long)(n0 + sr + 64) * ldb + ks + ske;

  const int wr = wave >> 1, wc = wave & 1;            // 2x2 waves of 64x64
  const int fr = lane & 15, fk = (lane >> 4) * 8;
  const int rAo = (wr * 64 + fr) * 32 + fk;
  const int rBo = (wc * 64 + fr) * 32 + fk;

  f32x4 zero = {0.f, 0.f, 0.f, 0.f};
  f32x4 acc[4][4];
#pragma unroll
  for (int m = 0; m < 4; ++m)
#pragma unroll
    for (int n = 0; n < 4; ++n) acc[m][n] = zero;

  auto STAGE = [&](u16* dA, u16* dB, int t) {
    const int kk = t << 5;
    gload16(gA0 + kk, dA + wave * 512);
    gload16(gA1 + kk, dA + 2048 + wave * 512);
    gload16(gB0 + kk, dB + wave * 512);
    gload16(gB1 + kk, dB + 2048 + wave * 512);
  };
  auto COMPUTE = [&](const u16* bA, const u16* bB) {
    bf16x8 av[4], bv[4];
#pragma unroll
    for (int m = 0; m < 4; ++m) av[m] = *(const bf16x8*)(bA + rAo + m * 512);
#pragma unroll
    for (int n = 0; n < 4; ++n) bv[n] = *(const bf16x8*)(bB + rBo + n * 512);
#pragma unroll
    for (int m = 0; m < 4; ++m)
#pragma unroll
      for (int n = 0; n < 4; ++n)
        acc[m][n] = __builtin_amdgcn_mfma_f32_16x16x32_bf16(av[m], bv[n], acc[m][n], 0, 0, 0);
  };

  // r5-validated pipeline: stage K-step (t+2), counted vmcnt(8) keeps two tiles
  // in flight (never 0 in steady state), barrier, compute K-step t.
#define PIPE(SA, SB, KIDX, CA, CB)                                   \
  STAGE(SA, SB, KIDX);                                               \
  asm volatile("s_waitcnt vmcnt(8)" ::: "memory");                   \
  __builtin_amdgcn_s_barrier();                                      \
  asm volatile("" ::: "memory");                                     \
  COMPUTE(CA, CB);                                                   \
  asm volatile("" ::: "memory");                                     \
  __builtin_amdgcn_s_barrier();                                      \
  asm volatile("" ::: "memory");

  const int nt = klen >> 5;            // (nt-2) % 3 == 0 by construction
  STAGE(sA[0], sB[0], 0);
  STAGE(sA[1], sB[1], 1);
  for (int t = 0; t + 2 < nt; t += 3) {
    PIPE(sA[2], sB[2], t + 2, sA[0], sB[0]);
    PIPE(sA[0], sB[0], t + 3, sA[1], sB[1]);
    PIPE(sA[1], sB[1], t + 4, sA[2], sB[2]);
  }
  asm volatile("s_waitcnt vmcnt(4)" ::: "memory");
  __builtin_amdgcn_s_barrier();
  asm volatile("" ::: "memory");
  COMPUTE(sA[0], sB[0]);               // K-step nt-2
  asm volatile("s_waitcnt vmcnt(0)" ::: "memory");
  __builtin_amdgcn_s_barrier();
  asm volatile("" ::: "memory");
  COMPUTE(sA[1], sB[1]);               // K-step nt-1
#undef PIPE

  // epilogue: C/D map col=lane&15, row=(lane>>4)*4+j  (guide m89/m91)
  const int er = m0 + wr * 64 + (lane >> 4) * 4;
  const int ec = n0 + wc * 64 + fr;
  if (MODE == 0) {
    u16* Hz = H + (long)zi * hZ;
#pragma unroll
    for (int m = 0; m < 4; ++m)
#pragma unroll
      for (int n = 0; n < 4; ++n) {
        f32x4 v = acc[m][n];
        int rb = er + m * 16, cb = ec + n * 16;
#pragma unroll
        for (int j = 0; j < 4; ++j)
          Hz[(long)(rb + j) * FDIM + cb] = f2bf(gelu_exact(v[j]));
      }
  } else if (MODE == 1) {
    float* Cz = C + (long)(ebase + zi) * cZ;
#pragma unroll
    for (int m = 0; m < 4; ++m)
#pragma unroll
      for (int n = 0; n < 4; ++n) {
        f32x4 v = acc[m][n];
        int rb = er + m * 16, cb = ec + n * 16;
#pragma unroll
        for (int j = 0; j < 4; ++j)
          Cz[(long)(rb + j) * DDIM + cb] = v[j];
      }
  } else {
    float* Cz = C + (long)bz * cZ;     // private (g,ks) slice, disjoint -> pure write
#pragma unroll
    for (int m = 0; m < 4; ++m)
#pragma unroll
      for (int n = 0; n < 4; ++n) {
        f32x4 v = acc[m][n];
        int rb = er + m * 16, cb = ec + n * 16;
#pragma unroll
        for (int j = 0; j < 4; ++j)
          Cz[(long)(rb + j) * DDIM + cb] = v[j];
      }
  }
}

// ---------- combine (gate-weighted gather) + general + residual + LayerNorm ----------
__global__ __launch_bounds__(256) void combine_ln_kernel(
    const float* __restrict__ x, const float* __restrict__ moe_bias,
    const float* __restrict__ Eout, const float* __restrict__ gen_p,
    const float* __restrict__ gb,
    const int* __restrict__ pos, const float* __restrict__ gates,
    const float* __restrict__ gamma, const float* __restrict__ beta,
    float* __restrict__ out)
{
  const int b = blockIdx.x, tid = threadIdx.x;
  const int lane = tid & 63, wave = tid >> 6;
  const long base = (long)b * DDIM;
  __shared__ int posr[NE];
  __shared__ float gr[NE];
  __shared__ float red[4];
  if (tid < NE) { posr[tid] = pos[(long)b * NE + tid]; gr[tid] = gates[(long)b * NE + tid]; }
  __syncthreads();
  float y[4];
  float ls = 0.f;
#pragma unroll
  for (int i = 0; i < 4; ++i) {
    int d = tid + i * 256;
    long idx = base + d;
    float moe = moe_bias[idx];
#pragma unroll
    for (int e = 0; e < NE; ++e) {
      int p = posr[e];                                  // block-uniform -> no divergence
      if (p >= 0) moe += gr[e] * Eout[((long)e * B_TOK + p) * DDIM + d];
    }
    moe = bfround(moe);                                 // matches ref's bf16 cast of moe_out
    float ge = gb[d] + gb[DDIM + d];
#pragma unroll
    for (int sl = 0; sl < 8; ++sl) ge += gen_p[(long)sl * BD + idx];
    y[i] = moe + ge + x[idx];
    ls += y[i];
  }
  float t = waveSum(ls);
  if (lane == 0) red[wave] = t;
  __syncthreads();
  float mean = (red[0] + red[1] + red[2] + red[3]) * (1.0f / DDIM);
  __syncthreads();
  float vs = 0.f;
#pragma unroll
  for (int i = 0; i < 4; ++i) { float d2 = y[i] - mean; vs += d2 * d2; }
  t = waveSum(vs);
  if (lane == 0) red[wave] = t;
  __syncthreads();
  float var = (red[0] + red[1] + red[2] + red[3]) * (1.0f / DDIM);
  float inv = rsqrtf(var + 1e-5f);
#pragma unroll
  for (int i = 0; i < 4; ++i) {
    int d = tid + i * 256;
    out[base + d] = (y[i] - mean) * inv * gamma[d] + beta[d];
  }
}

// ---------- orchestration ----------
extern "C" void kernel_launch(void* const* d_in, const int* in_sizes, int n_in,
                              void* d_out, int out_size, void* d_ws, size_t ws_size,
                              hipStream_t stream)
{
  const float* x      = (const float*)d_in[0];
  const float* logits = (const float*)d_in[1];
  const int*   masks  = (const int*)d_in[2];
  const float* ew_in  = (const float*)d_in[3];
  const float* ew_out = (const float*)d_in[4];
  const float* eb_out = (const float*)d_in[5];
  const float* gw_in  = (const float*)d_in[6];
  const float* gw_out = (const float*)d_in[7];
  const float* gb_out = (const float*)d_in[8];
  const float* gamma  = (const float*)d_in[9];
  const float* beta   = (const float*)d_in[10];
  float* out = (float*)d_out;

  char* w = (char*)d_ws;
  size_t off = 0;
  auto alloc = [&](size_t bytes) -> void* {
    off = (off + 4095) & ~(size_t)4095;
    void* p = w + off; off += bytes; return p;
  };
  const long DF = (long)DDIM * FDIM;          // 4.19M elems
  const long BF = (long)B_TOK * FDIM;         // 8.39M elems

  float* gates    = (float*)alloc((size_t)B_TOK * NE * 4);
  float* loss     = (float*)alloc(64 * 4);
  int*   tok      = (int*)alloc((size_t)NE * B_TOK * 4);
  int*   pos      = (int*)alloc((size_t)B_TOK * NE * 4);
  int*   cnts     = (int*)alloc(2 * NE * 4);
  u16*   xb       = (u16*)alloc((size_t)BD * 2);
  float* moe_bias = (float*)alloc((size_t)BD * 4);
  float* gen_p    = (float*)alloc(8 * (size_t)BD * 4);           // 8 slices (g,ks)
  float* Eout     = (float*)alloc((size_t)NE * BD * 4);          // per-expert compact f32

  // routed chunk size adaptive to remaining ws
  const size_t per = 2 * (size_t)DF * 2 + (size_t)BF * 2 + 3 * 4096; // WinT+WoutT+Hb per expert
  int CE = 16;
  while (CE > 1 && off + (size_t)CE * per > ws_size) CE >>= 1;
  u16* WinT  = (u16*)alloc((size_t)CE * DF * 2);
  u16* WoutT = (u16*)alloc((size_t)CE * DF * 2);
  u16* Hb    = (u16*)alloc((size_t)CE * BF * 2);

  hipMemsetAsync(loss, 0, 64 * 4, stream);
  gating_kernel<<<8, 256, 0, stream>>>(logits, masks, gates, loss);
  finalize_loss<<<1, 64, 0, stream>>>(loss, out + BD);
  compact_kernel<<<NE, 256, 0, stream>>>(masks, tok, pos, cnts);
  cvt_x_kernel<<<2048, 256, 0, stream>>>(x, xb);
  bias_init_kernel<<<8192, 256, 0, stream>>>(gates, eb_out, moe_bias);

  for (int e0 = 0; e0 < NE; e0 += CE) {
    transpose_cvt<<<dim3(FDIM/64, DDIM/64, CE), 256, 0, stream>>>(
        ew_in + (long)e0 * DF, WinT, DDIM, FDIM, DF, DF);
    transpose_cvt<<<dim3(DDIM/64, FDIM/64, CE), 256, 0, stream>>>(
        ew_out + (long)e0 * DF, WoutT, FDIM, DDIM, DF, DF);
    // in-proj: [cnt_pad,1024] x [4096,1024]^T -> Hb (bf16 gelu), K=1024
    gemm128<0><<<dim3(FDIM/128, B_TOK/128, CE), 256, 0, stream>>>(
        xb, DDIM, 0L, WinT, DDIM, DF, DDIM,
        Hb, BF, nullptr, 0L, tok, cnts, e0);
    // out-proj: [cnt_pad,4096] x [1024,4096]^T -> Eout (f32, compact, full-K)
    gemm128<1><<<dim3(DDIM/128, B_TOK/128, CE), 256, 0, stream>>>(
        Hb, FDIM, BF, WoutT, FDIM, DF, FDIM,
        nullptr, 0L, Eout, BD, nullptr, cnts, e0);
  }

  // general experts: reuse WinT/WoutT/Hb scratch (CE >= 2 given ws sizing)
  transpose_cvt<<<dim3(FDIM/64, DDIM/64, NG), 256, 0, stream>>>(
      gw_in, WinT, DDIM, FDIM, DF, DF);
  transpose_cvt<<<dim3(DDIM/64, FDIM/64, NG), 256, 0, stream>>>(
      gw_out, WoutT, FDIM, DDIM, DF, DF);
  gemm128<0><<<dim3(FDIM/128, B_TOK/128, NG), 256, 0, stream>>>(
      xb, DDIM, 0L, WinT, DDIM, DF, DDIM,
      Hb, BF, nullptr, 0L, nullptr, nullptr, 0);
  // general out-proj: K-split 4 (bz = g*4+ks), klen = 1024, disjoint slice writes
  gemm128<2><<<dim3(DDIM/128, B_TOK/128, NG * 4), 256, 0, stream>>>(
      Hb, FDIM, BF, WoutT, FDIM, DF, FDIM / 4,
      nullptr, 0L, gen_p, BD, nullptr, nullptr, 0);

  combine_ln_kernel<<<B_TOK, 256, 0, stream>>>(
      x, moe_bias, Eout, gen_p, gb_out, pos, gates, gamma, beta, out);
}

// Round 14
// 746.550 us; speedup vs baseline: 1.0568x; 1.0236x over previous
//
#include <hip/hip_runtime.h>
#include <hip/hip_bf16.h>

#define B_TOK 2048
#define DDIM 1024
#define FDIM 4096
#define NE 16
#define NG 2
#define BD ((long)B_TOK * DDIM)

typedef unsigned short u16;
typedef __attribute__((ext_vector_type(8))) short bf16x8;   // 8 bf16 (4 VGPRs)
typedef __attribute__((ext_vector_type(4))) float f32x4;

// ---------- helpers ----------
__device__ inline u16 f2bf(float x) {           // RNE f32 -> bf16 bits
  union { float f; unsigned u; } v; v.f = x;
  return (u16)((v.u + 0x7fffu + ((v.u >> 16) & 1u)) >> 16);
}
__device__ inline float bf2f(u16 b) {
  union { float f; unsigned u; } v; v.u = ((unsigned)b) << 16; return v.f;
}
__device__ inline float bfround(float x) {      // f32 -> bf16 -> f32 (matches astype(bf16))
  union { float f; unsigned u; } v; v.f = x;
  v.u = ((v.u + 0x7fffu + ((v.u >> 16) & 1u)) >> 16) << 16;
  return v.f;
}
// Abramowitz-Stegun 7.1.26 erf, |eps| <= 1.5e-7
__device__ inline float fast_erf(float x) {
  float ax = fabsf(x);
  float t = __builtin_amdgcn_rcpf(1.0f + 0.3275911f * ax);
  float poly = t * (0.254829592f + t * (-0.284496736f + t * (1.421413741f +
               t * (-1.453152027f + t * 1.061405429f))));
  float r = 1.0f - poly * __expf(-ax * ax);
  return copysignf(r, x);
}
__device__ inline float gelu_exact(float x) {
  return 0.5f * x * (1.0f + fast_erf(x * 0.70710678118654752440f));
}
__device__ inline void gload16(const void* g, void* l) {
  // LDS dest is wave-uniform base; HW adds lane*16 (guide m104/m108).
  __builtin_amdgcn_global_load_lds((const __attribute__((address_space(1))) void*)g,
                                   (__attribute__((address_space(3))) void*)l, 16, 0, 0);
}
__device__ inline float waveSum(float v) {
  v += __shfl_down(v, 32); v += __shfl_down(v, 16); v += __shfl_down(v, 8);
  v += __shfl_down(v, 4);  v += __shfl_down(v, 2);  v += __shfl_down(v, 1);
  return v;
}

// ---------- gating + loss partials ----------
__global__ __launch_bounds__(256) void gating_kernel(
    const float* __restrict__ logits, const int* __restrict__ masks,
    float* __restrict__ gates, float* __restrict__ loss)
{
  const int b = blockIdx.x * 256 + threadIdx.x;       // grid 8 x 256 == 2048
  const int lane = threadIdx.x & 63;
  const float* lr = logits + (long)b * NE;
  const int*   mr = masks  + (long)b * NE;
  float raw[NE]; int mk[NE];
  float mx = -1e30f;
#pragma unroll
  for (int e = 0; e < NE; ++e) { raw[e] = lr[e]; mx = fmaxf(mx, raw[e]); }
  float s = 0.f;
#pragma unroll
  for (int e = 0; e < NE; ++e) { raw[e] = expf(raw[e] - mx); s += raw[e]; }
  float inv = 1.0f / s;
#pragma unroll
  for (int e = 0; e < NE; ++e) raw[e] *= inv;
  float gs = 0.f;
#pragma unroll
  for (int e = 0; e < NE; ++e) { mk[e] = (mr[e] == 1); gs += mk[e] ? raw[e] : 0.f; }
  float ginv = 1.0f / (gs + 1e-9f);
  float* gr = gates + (long)b * NE;
#pragma unroll
  for (int e = 0; e < NE; ++e) gr[e] = (mk[e] ? raw[e] : 0.f) * ginv;
#pragma unroll
  for (int e = 0; e < NE; ++e) {
    float cs = waveSum(raw[e]);
    float cc = waveSum(mk[e] ? 1.f : 0.f);
    if (lane == 0) { atomicAdd(&loss[e], cs); atomicAdd(&loss[NE + e], cc); }
  }
  float t = waveSum(gs);
  if (lane == 0) atomicAdd(&loss[32], t);
}

__global__ void finalize_loss(const float* __restrict__ loss, float* __restrict__ out2) {
  if (threadIdx.x == 0) {
    float aug = 0.f;
    for (int e = 0; e < NE; ++e)
      aug += (loss[e] / (float)B_TOK) * (loss[NE + e] / (float)B_TOK);
    aug *= (1.0f / NE);
    float s = loss[32] / (float)B_TOK;
    out2[0] = aug;
    out2[1] = (1.f - s) * (1.f - s);
  }
}

// ---------- deterministic per-expert token compaction + inverse map ----------
__global__ __launch_bounds__(256) void compact_kernel(
    const int* __restrict__ masks, int* __restrict__ tok,
    int* __restrict__ pos, int* __restrict__ cnts)
{
  const int e = blockIdx.x, tid = threadIdx.x;
  const int lane = tid & 63, wave = tid >> 6;
  __shared__ int wcnt[4];
  __shared__ int runbase;
  if (tid == 0) runbase = 0;
  __syncthreads();
  for (int b0 = 0; b0 < B_TOK; b0 += 256) {
    int b = b0 + tid;
    int m = (masks[(long)b * NE + e] == 1);
    unsigned long long bal = __ballot(m);
    int pre = __popcll(bal & ((1ull << lane) - 1ull));
    if (lane == 0) wcnt[wave] = __popcll(bal);
    __syncthreads();
    int base = runbase;
    for (int w = 0; w < wave; ++w) base += wcnt[w];
    if (m) {
      int p = base + pre;
      tok[(e << 11) + p] = b;
      pos[(long)b * NE + e] = p;
    } else {
      pos[(long)b * NE + e] = -1;
    }
    __syncthreads();
    if (tid == 0) runbase += wcnt[0] + wcnt[1] + wcnt[2] + wcnt[3];
    __syncthreads();
  }
  const int cnt = runbase;
  const int cnt_pad = (cnt + 127) & ~127;
  for (int i = cnt + tid; i < cnt_pad; i += 256)
    tok[(e << 11) + i] = 0;          // safe row; pad output rows never read
  if (tid == 0) { cnts[e] = cnt; cnts[NE + e] = cnt_pad; }
}

// ---------- x f32 -> bf16 ----------
__global__ __launch_bounds__(256) void cvt_x_kernel(const float* __restrict__ x, u16* __restrict__ xb) {
  long i = ((long)blockIdx.x * 256 + threadIdx.x) * 4;
  float4 v = *(const float4*)&x[i];
  ushort4 o; o.x = f2bf(v.x); o.y = f2bf(v.y); o.z = f2bf(v.z); o.w = f2bf(v.w);
  *(ushort4*)&xb[i] = o;
}

// ---------- moe bias: moe_bias[b,d] = sum_e gates[b,e]*eb[e,d] ----------
__global__ __launch_bounds__(256) void bias_init_kernel(
    const float* __restrict__ gates, const float* __restrict__ eb,
    float* __restrict__ moe_bias)
{
  long i = (long)blockIdx.x * 256 + threadIdx.x;       // grid 8192 -> B*D
  int b = (int)(i >> 10), d = (int)(i & 1023);
  const float* gr = gates + (long)b * NE;
  float s = 0.f;
#pragma unroll
  for (int e = 0; e < NE; ++e) s += gr[e] * eb[e * DDIM + d];
  moe_bias[i] = s;
}

// ---------- transpose + f32->bf16: src [R,C] -> dst [C,R] ----------
__global__ __launch_bounds__(256) void transpose_cvt(
    const float* __restrict__ src, u16* __restrict__ dst,
    int R, int C, long sZ, long dZ)
{
  __shared__ float t[64][65];
  const float* s = src + (long)blockIdx.z * sZ;
  u16* d = dst + (long)blockIdx.z * dZ;
  const int c0 = blockIdx.x * 64, r0 = blockIdx.y * 64;
  const int tid = threadIdx.x;
#pragma unroll
  for (int it = 0; it < 4; ++it) {
    int idx = tid + it * 256;
    int r = idx >> 4, cq = (idx & 15) * 4;
    float4 v = *(const float4*)&s[(long)(r0 + r) * C + c0 + cq];
    t[r][cq] = v.x; t[r][cq + 1] = v.y; t[r][cq + 2] = v.z; t[r][cq + 3] = v.w;
  }
  __syncthreads();
#pragma unroll
  for (int it = 0; it < 4; ++it) {
    int idx = tid + it * 256;
    int c = idx >> 4, rq = (idx & 15) * 4;
    ushort4 o;
    o.x = f2bf(t[rq][c]); o.y = f2bf(t[rq+1][c]); o.z = f2bf(t[rq+2][c]); o.w = f2bf(t[rq+3][c]);
    *(ushort4*)&d[(long)(c0 + c) * R + r0 + rq] = o;
  }
}

// ---------- 128x128 bf16 MFMA GEMM — r5-validated 3-buffer counted-vmcnt ring,
// + 4x4 super-tile raster within each z (bijective; chunk alignment preserved:
// 16 z per dispatch => each XCD chunk covers exactly 2 experts).
// klen is a RUNTIME arg on purpose (constexpr K unrolled the t-loop in r9:
// VGPR 84->100, occupancy halved). Do not make it constexpr.
// ALL MODES write bf16 via H (r14: Eout/gen_p quantized to bf16 — pure HBM
// traffic win; error ~1e-3, margin 0.031 vs 0.0975 threshold).
// MODE 0 (in-proj): A rows gathered via tok (tok!=null) else identity.
//   H[zi] = bf16(gelu(acc)), row stride FDIM.
// MODE 1 (out-proj routed): A = Hb[zi] compact rows, full-K.
//   H[ebase+zi] = bf16(acc), row stride DDIM.
// MODE 2 (out-proj general): bz = g*4+ks, K-split 4, klen=FDIM/4.
//   H[bz] = bf16(acc) (disjoint per-slice tiles), row stride DDIM.
template<int MODE>
__global__ __launch_bounds__(256) void gemm128(
    const u16* __restrict__ A, int lda, long aZ,
    const u16* __restrict__ Bm, int ldb, long bZ,
    int klen,
    u16* __restrict__ H, long hZ,
    const int* __restrict__ tok, const int* __restrict__ cnts, int ebase)
{
  // bijective chunked XCD swizzle (T divisible by 8 by construction)
  int lin = ((int)blockIdx.z * gridDim.y + blockIdx.y) * gridDim.x + blockIdx.x;
  const int T = gridDim.x * gridDim.y * gridDim.z;
  lin = (lin & 7) * (T >> 3) + (lin >> 3);
  // 4x4 super-tile decode within z: consecutive lin traverse a 4x4 tile block
  // (gridDim.x, gridDim.y both divisible by 4 for all launches here).
  const int PZ = gridDim.x * gridDim.y;
  const int bz = lin / PZ;
  const int r  = lin - bz * PZ;
  const int nSx = gridDim.x >> 2;
  const int st = r >> 4, pos = r & 15;
  const int bx = ((st % nSx) << 2) + (pos & 3);
  const int by = ((st / nSx) << 2) + (pos >> 2);

  const int zi = (MODE == 2) ? (bz >> 2) : bz;
  const int ks = (MODE == 2) ? (bz & 3) * klen : 0;
  const int m0 = by * 128, n0 = bx * 128;
  if (MODE != 2 && cnts && m0 >= cnts[NE + ebase + zi]) return;

  __shared__ u16 sA[3][128 * 32];
  __shared__ u16 sB[3][128 * 32];
  const u16* Az = A + (long)zi * aZ;
  const u16* Bz = Bm + (long)zi * bZ;
  const int tid = threadIdx.x, lane = tid & 63, wave = tid >> 6;

  // staging: linear LDS, 2 passes of 16B/thread per operand
  const int off = tid * 16;            // byte offset in 8KB tile (pass 0)
  const int sr  = off >> 6;            // row 0..63 (64B per row of 32 bf16)
  const int ske = (off & 63) >> 1;     // k element offset within row
  int arow0 = m0 + sr, arow1 = m0 + sr + 64;
  if (MODE == 0 && tok) {              // gather source rows (per-lane global ok)
    const int* tz = tok + ((ebase + zi) << 11);
    arow0 = tz[arow0]; arow1 = tz[arow1];
  }
  const u16* gA0 = Az + (long)arow0 * lda + ks + ske;
  const u16* gA1 = Az + (long)arow1 * lda + ks + ske;
  const u16* gB0 = Bz + (long)(n0 + sr) * ldb + ks + ske;
  const u16* gB1 = Bz + (long)(n0 + sr + 64) * ldb + ks + ske;

  const int wr = wave >> 1, wc = wave & 1;            // 2x2 waves of 64x64
  const int fr = lane & 15, fk = (lane >> 4) * 8;
  const int rAo = (wr * 64 + fr) * 32 + fk;
  const int rBo = (wc * 64 + fr) * 32 + fk;

  f32x4 zero = {0.f, 0.f, 0.f, 0.f};
  f32x4 acc[4][4];
#pragma unroll
  for (int m = 0; m < 4; ++m)
#pragma unroll
    for (int n = 0; n < 4; ++n) acc[m][n] = zero;

  auto STAGE = [&](u16* dA, u16* dB, int t) {
    const int kk = t << 5;
    gload16(gA0 + kk, dA + wave * 512);
    gload16(gA1 + kk, dA + 2048 + wave * 512);
    gload16(gB0 + kk, dB + wave * 512);
    gload16(gB1 + kk, dB + 2048 + wave * 512);
  };
  auto COMPUTE = [&](const u16* bA, const u16* bB) {
    bf16x8 av[4], bv[4];
#pragma unroll
    for (int m = 0; m < 4; ++m) av[m] = *(const bf16x8*)(bA + rAo + m * 512);
#pragma unroll
    for (int n = 0; n < 4; ++n) bv[n] = *(const bf16x8*)(bB + rBo + n * 512);
#pragma unroll
    for (int m = 0; m < 4; ++m)
#pragma unroll
      for (int n = 0; n < 4; ++n)
        acc[m][n] = __builtin_amdgcn_mfma_f32_16x16x32_bf16(av[m], bv[n], acc[m][n], 0, 0, 0);
  };

  // r5-validated pipeline: stage K-step (t+2), counted vmcnt(8) keeps two tiles
  // in flight (never 0 in steady state), barrier, compute K-step t.
#define PIPE(SA, SB, KIDX, CA, CB)                                   \
  STAGE(SA, SB, KIDX);                                               \
  asm volatile("s_waitcnt vmcnt(8)" ::: "memory");                   \
  __builtin_amdgcn_s_barrier();                                      \
  asm volatile("" ::: "memory");                                     \
  COMPUTE(CA, CB);                                                   \
  asm volatile("" ::: "memory");                                     \
  __builtin_amdgcn_s_barrier();                                      \
  asm volatile("" ::: "memory");

  const int nt = klen >> 5;            // (nt-2) % 3 == 0 by construction
  STAGE(sA[0], sB[0], 0);
  STAGE(sA[1], sB[1], 1);
  for (int t = 0; t + 2 < nt; t += 3) {
    PIPE(sA[2], sB[2], t + 2, sA[0], sB[0]);
    PIPE(sA[0], sB[0], t + 3, sA[1], sB[1]);
    PIPE(sA[1], sB[1], t + 4, sA[2], sB[2]);
  }
  asm volatile("s_waitcnt vmcnt(4)" ::: "memory");
  __builtin_amdgcn_s_barrier();
  asm volatile("" ::: "memory");
  COMPUTE(sA[0], sB[0]);               // K-step nt-2
  asm volatile("s_waitcnt vmcnt(0)" ::: "memory");
  __builtin_amdgcn_s_barrier();
  asm volatile("" ::: "memory");
  COMPUTE(sA[1], sB[1]);               // K-step nt-1
#undef PIPE

  // epilogue: C/D map col=lane&15, row=(lane>>4)*4+j  (guide m89/m91)
  const int er = m0 + wr * 64 + (lane >> 4) * 4;
  const int ec = n0 + wc * 64 + fr;
  const int rstride = (MODE == 0) ? FDIM : DDIM;
  u16* Hz;
  if (MODE == 0)      Hz = H + (long)zi * hZ;
  else if (MODE == 1) Hz = H + (long)(ebase + zi) * hZ;
  else                Hz = H + (long)bz * hZ;
#pragma unroll
  for (int m = 0; m < 4; ++m)
#pragma unroll
    for (int n = 0; n < 4; ++n) {
      f32x4 v = acc[m][n];
      int rb = er + m * 16, cb = ec + n * 16;
#pragma unroll
      for (int j = 0; j < 4; ++j) {
        float val = (MODE == 0) ? gelu_exact(v[j]) : v[j];
        Hz[(long)(rb + j) * rstride + cb] = f2bf(val);
      }
    }
}

// ---------- combine (gate-weighted gather) + general + residual + LayerNorm ----------
__global__ __launch_bounds__(256) void combine_ln_kernel(
    const float* __restrict__ x, const float* __restrict__ moe_bias,
    const u16* __restrict__ Eout, const u16* __restrict__ gen_p,
    const float* __restrict__ gb,
    const int* __restrict__ pos, const float* __restrict__ gates,
    const float* __restrict__ gamma, const float* __restrict__ beta,
    float* __restrict__ out)
{
  const int b = blockIdx.x, tid = threadIdx.x;
  const int lane = tid & 63, wave = tid >> 6;
  const long base = (long)b * DDIM;
  __shared__ int posr[NE];
  __shared__ float gr[NE];
  __shared__ float red[4];
  if (tid < NE) { posr[tid] = pos[(long)b * NE + tid]; gr[tid] = gates[(long)b * NE + tid]; }
  __syncthreads();
  float y[4];
  float ls = 0.f;
#pragma unroll
  for (int i = 0; i < 4; ++i) {
    int d = tid + i * 256;
    long idx = base + d;
    float moe = moe_bias[idx];
#pragma unroll
    for (int e = 0; e < NE; ++e) {
      int p = posr[e];                                  // block-uniform -> no divergence
      if (p >= 0) moe += gr[e] * bf2f(Eout[((long)e * B_TOK + p) * DDIM + d]);
    }
    moe = bfround(moe);                                 // matches ref's bf16 cast of moe_out
    float ge = gb[d] + gb[DDIM + d];
#pragma unroll
    for (int sl = 0; sl < 8; ++sl) ge += bf2f(gen_p[(long)sl * BD + idx]);
    y[i] = moe + ge + x[idx];
    ls += y[i];
  }
  float t = waveSum(ls);
  if (lane == 0) red[wave] = t;
  __syncthreads();
  float mean = (red[0] + red[1] + red[2] + red[3]) * (1.0f / DDIM);
  __syncthreads();
  float vs = 0.f;
#pragma unroll
  for (int i = 0; i < 4; ++i) { float d2 = y[i] - mean; vs += d2 * d2; }
  t = waveSum(vs);
  if (lane == 0) red[wave] = t;
  __syncthreads();
  float var = (red[0] + red[1] + red[2] + red[3]) * (1.0f / DDIM);
  float inv = rsqrtf(var + 1e-5f);
#pragma unroll
  for (int i = 0; i < 4; ++i) {
    int d = tid + i * 256;
    out[base + d] = (y[i] - mean) * inv * gamma[d] + beta[d];
  }
}

// ---------- orchestration ----------
extern "C" void kernel_launch(void* const* d_in, const int* in_sizes, int n_in,
                              void* d_out, int out_size, void* d_ws, size_t ws_size,
                              hipStream_t stream)
{
  const float* x      = (const float*)d_in[0];
  const float* logits = (const float*)d_in[1];
  const int*   masks  = (const int*)d_in[2];
  const float* ew_in  = (const float*)d_in[3];
  const float* ew_out = (const float*)d_in[4];
  const float* eb_out = (const float*)d_in[5];
  const float* gw_in  = (const float*)d_in[6];
  const float* gw_out = (const float*)d_in[7];
  const float* gb_out = (const float*)d_in[8];
  const float* gamma  = (const float*)d_in[9];
  const float* beta   = (const float*)d_in[10];
  float* out = (float*)d_out;

  char* w = (char*)d_ws;
  size_t off = 0;
  auto alloc = [&](size_t bytes) -> void* {
    off = (off + 4095) & ~(size_t)4095;
    void* p = w + off; off += bytes; return p;
  };
  const long DF = (long)DDIM * FDIM;          // 4.19M elems
  const long BF = (long)B_TOK * FDIM;         // 8.39M elems

  float* gates    = (float*)alloc((size_t)B_TOK * NE * 4);
  float* loss     = (float*)alloc(64 * 4);
  int*   tok      = (int*)alloc((size_t)NE * B_TOK * 4);
  int*   pos      = (int*)alloc((size_t)B_TOK * NE * 4);
  int*   cnts     = (int*)alloc(2 * NE * 4);
  u16*   xb       = (u16*)alloc((size_t)BD * 2);
  float* moe_bias = (float*)alloc((size_t)BD * 4);
  u16*   gen_p    = (u16*)alloc(8 * (size_t)BD * 2);             // 8 slices (g,ks), bf16
  u16*   Eout     = (u16*)alloc((size_t)NE * BD * 2);            // per-expert compact bf16

  // routed chunk size adaptive to remaining ws
  const size_t per = 2 * (size_t)DF * 2 + (size_t)BF * 2 + 3 * 4096; // WinT+WoutT+Hb per expert
  int CE = 16;
  while (CE > 1 && off + (size_t)CE * per > ws_size) CE >>= 1;
  u16* WinT  = (u16*)alloc((size_t)CE * DF * 2);
  u16* WoutT = (u16*)alloc((size_t)CE * DF * 2);
  u16* Hb    = (u16*)alloc((size_t)CE * BF * 2);

  hipMemsetAsync(loss, 0, 64 * 4, stream);
  gating_kernel<<<8, 256, 0, stream>>>(logits, masks, gates, loss);
  finalize_loss<<<1, 64, 0, stream>>>(loss, out + BD);
  compact_kernel<<<NE, 256, 0, stream>>>(masks, tok, pos, cnts);
  cvt_x_kernel<<<2048, 256, 0, stream>>>(x, xb);
  bias_init_kernel<<<8192, 256, 0, stream>>>(gates, eb_out, moe_bias);

  for (int e0 = 0; e0 < NE; e0 += CE) {
    transpose_cvt<<<dim3(FDIM/64, DDIM/64, CE), 256, 0, stream>>>(
        ew_in + (long)e0 * DF, WinT, DDIM, FDIM, DF, DF);
    transpose_cvt<<<dim3(DDIM/64, FDIM/64, CE), 256, 0, stream>>>(
        ew_out + (long)e0 * DF, WoutT, FDIM, DDIM, DF, DF);
    // in-proj: [cnt_pad,1024] x [4096,1024]^T -> Hb (bf16 gelu), K=1024
    gemm128<0><<<dim3(FDIM/128, B_TOK/128, CE), 256, 0, stream>>>(
        xb, DDIM, 0L, WinT, DDIM, DF, DDIM,
        Hb, BF, tok, cnts, e0);
    // out-proj: [cnt_pad,4096] x [1024,4096]^T -> Eout (bf16, compact, full-K)
    gemm128<1><<<dim3(DDIM/128, B_TOK/128, CE), 256, 0, stream>>>(
        Hb, FDIM, BF, WoutT, FDIM, DF, FDIM,
        Eout, BD, nullptr, cnts, e0);
  }

  // general experts: reuse WinT/WoutT/Hb scratch (CE >= 2 given ws sizing)
  transpose_cvt<<<dim3(FDIM/64, DDIM/64, NG), 256, 0, stream>>>(
      gw_in, WinT, DDIM, FDIM, DF, DF);
  transpose_cvt<<<dim3(DDIM/64, FDIM/64, NG), 256, 0, stream>>>(
      gw_out, WoutT, FDIM, DDIM, DF, DF);
  gemm128<0><<<dim3(FDIM/128, B_TOK/128, NG), 256, 0, stream>>>(
      xb, DDIM, 0L, WinT, DDIM, DF, DDIM,
      Hb, BF, nullptr, nullptr, 0);
  // general out-proj: K-split 4 (bz = g*4+ks), klen = 1024, disjoint slice writes
  gemm128<2><<<dim3(DDIM/128, B_TOK/128, NG * 4), 256, 0, stream>>>(
      Hb, FDIM, BF, WoutT, FDIM, DF, FDIM / 4,
      gen_p, BD, nullptr, nullptr, 0);

  combine_ln_kernel<<<B_TOK, 256, 0, stream>>>(
      x, moe_bias, Eout, gen_p, gb_out, pos, gates, gamma, beta, out);
}